// Round 3
// baseline (1401.853 us; speedup 1.0000x reference)
//
#include <hip/hip_runtime.h>
#include <math.h>

#define DDIM 256
#define BN 64
#define BK 64
#define BD 64

// XOR swizzle: row r, float4-column c4 (0..15) -> permuted float4 column.
__device__ __forceinline__ int swz(int r, int c4) {
    return c4 ^ ((r + (r >> 2)) & 15);
}

// ---- numpy pairwise-sum simulation (bit-faithful for n=256 contiguous) ----
// numpy: n=256 -> left(128)+right(128); each 128-block uses 8 accumulators
// r[j] = a[j]; for i=8..120 step 8: r[j]+=a[i+j]; combine ((r0+r1)+(r2+r3))+((r4+r5)+(r6+r7)).
// Lane l in [0,16) computes chain c_l: half=l>>3, j=l&7, 16 sequential terms.
// Elementwise square is rounded separately (contract off), as numpy's zf*zf temp.
__device__ __forceinline__ float np_sq_chain(const float* v, int lane) {
    #pragma clang fp contract(off)
    const int half = lane >> 3, j = lane & 7;
    const float* base = v + half * 128 + j;
    float x = base[0];
    float c = x * x;
    #pragma unroll
    for (int m = 1; m < 16; ++m) {
        float y = base[8 * m];
        float s = y * y;
        c = c + s;
    }
    return c;
}

__device__ __forceinline__ float np_combine16(const float* c) {
    #pragma clang fp contract(off)
    float L = ((c[0] + c[1]) + (c[2] + c[3])) + ((c[4] + c[5]) + (c[6] + c[7]));
    float R = ((c[8] + c[9]) + (c[10] + c[11])) + ((c[12] + c[13]) + (c[14] + c[15]));
    return L + R;
}

// ---------------- kernel 1: zero counts + sqsum ----------------
__global__ void zero_ws_kernel(int* __restrict__ counts, float* __restrict__ sqsum, int K) {
    int i = blockIdx.x * 256 + threadIdx.x;
    if (i < K) counts[i] = 0;
    if (i == K) *sqsum = 0.0f;
}

// ---------------- kernel 2: numpy-faithful code norms ||e_k||^2 ----------------
__global__ void code_norms_np_kernel(const float* __restrict__ e, float* __restrict__ e2) {
    __shared__ float buf[DDIM];
    __shared__ float ch[16];
    int k = blockIdx.x;
    int t = threadIdx.x;  // 64 threads = 1 wave
    float4 v = *(const float4*)&e[(size_t)k * DDIM + t * 4];
    *(float4*)&buf[t * 4] = v;
    __syncthreads();
    if (t < 16) ch[t] = np_sq_chain(buf, t);
    __syncthreads();
    if (t == 0) e2[k] = np_combine16(ch);
}

// ---------------- kernel 3: fast fp32 distance -> top-4 candidates/row ----------------
__global__ __launch_bounds__(256, 2)
void vq_argmin_kernel(const float* __restrict__ z, const float* __restrict__ e,
                      const float* __restrict__ e2, int* __restrict__ cand, int K) {
    __shared__ float zs[BN * BD];
    __shared__ float es[BK * BD];

    const int t  = threadIdx.x;
    const int tx = t & 15;
    const int ty = t >> 4;
    const int row0 = blockIdx.x * BN;

    float best[4], sec[4];
    int   bidx[4], sidx[4];
    #pragma unroll
    for (int i = 0; i < 4; ++i) {
        best[i] = 3.4e38f; sec[i] = 3.4e38f; bidx[i] = 0; sidx[i] = 0;
    }

    #pragma unroll 1
    for (int kt = 0; kt < K; kt += BK) {
        float acc[4][4];
        #pragma unroll
        for (int i = 0; i < 4; ++i)
            #pragma unroll
            for (int j = 0; j < 4; ++j) acc[i][j] = 0.0f;

        #pragma unroll 1
        for (int dc = 0; dc < DDIM; dc += BD) {
            #pragma unroll
            for (int p = 0; p < 4; ++p) {
                int q  = t + p * 256;
                int r  = q >> 4;
                int c4 = q & 15;
                float4 vz = *(const float4*)&z[(size_t)(row0 + r) * DDIM + dc + c4 * 4];
                float4 ve = *(const float4*)&e[(size_t)(kt  + r) * DDIM + dc + c4 * 4];
                *(float4*)&zs[r * BD + 4 * swz(r, c4)] = vz;
                *(float4*)&es[r * BD + 4 * swz(r, c4)] = ve;
            }
            __syncthreads();

            #pragma unroll
            for (int dd4 = 0; dd4 < 16; ++dd4) {
                float4 a[4], b[4];
                #pragma unroll
                for (int i = 0; i < 4; ++i) {
                    int r = ty * 4 + i;
                    a[i] = *(float4*)&zs[r * BD + 4 * swz(r, dd4)];
                }
                #pragma unroll
                for (int j = 0; j < 4; ++j) {
                    int r = tx * 4 + j;
                    b[j] = *(float4*)&es[r * BD + 4 * swz(r, dd4)];
                }
                #pragma unroll
                for (int i = 0; i < 4; ++i) {
                    #pragma unroll
                    for (int j = 0; j < 4; ++j) {
                        acc[i][j] = fmaf(a[i].x, b[j].x, acc[i][j]);
                        acc[i][j] = fmaf(a[i].y, b[j].y, acc[i][j]);
                        acc[i][j] = fmaf(a[i].z, b[j].z, acc[i][j]);
                        acc[i][j] = fmaf(a[i].w, b[j].w, acc[i][j]);
                    }
                }
            }
            __syncthreads();
        }

        #pragma unroll
        for (int j = 0; j < 4; ++j) {
            int k = kt + tx * 4 + j;
            float ev = e2[k];
            #pragma unroll
            for (int i = 0; i < 4; ++i) {
                float m = fmaf(-2.0f, acc[i][j], ev);
                if (m < best[i]) {
                    sec[i] = best[i]; sidx[i] = bidx[i];
                    best[i] = m;      bidx[i] = k;
                } else if (m < sec[i]) {
                    sec[i] = m; sidx[i] = k;
                }
            }
        }
    }

    // cross-thread reduction: per-row global top-4 (ties -> smaller index)
    __syncthreads();
    float* rmin = zs;          // [64][32] floats
    int*   ridx = (int*)es;    // [64][32] ints
    #pragma unroll
    for (int i = 0; i < 4; ++i) {
        int r = ty * 4 + i;
        rmin[r * 32 + tx * 2]     = best[i];
        rmin[r * 32 + tx * 2 + 1] = sec[i];
        ridx[r * 32 + tx * 2]     = bidx[i];
        ridx[r * 32 + tx * 2 + 1] = sidx[i];
    }
    __syncthreads();
    if (t < BN) {
        float bm[4] = {3.4e38f, 3.4e38f, 3.4e38f, 3.4e38f};
        int   bk[4] = {0x7fffffff, 0x7fffffff, 0x7fffffff, 0x7fffffff};
        for (int x = 0; x < 32; ++x) {
            float m  = rmin[t * 32 + x];
            int   k2 = ridx[t * 32 + x];
            #pragma unroll
            for (int c = 0; c < 4; ++c) {
                if (m < bm[c] || (m == bm[c] && k2 < bk[c])) {
                    for (int d = 3; d > c; --d) { bm[d] = bm[d-1]; bk[d] = bk[d-1]; }
                    bm[c] = m; bk[c] = k2;
                    break;
                }
            }
        }
        #pragma unroll
        for (int c = 0; c < 4; ++c) cand[4 * (row0 + t) + c] = bk[c];
    }
}

// ---------------- kernel 3b: numpy-fp32-faithful re-ranking of top-4 ----------------
// One wave per row. d_np(k) = fl32(sqrt(max(fl32(fl32(s_x - 2*dot) + s_e), 0)))
// with s_x via numpy pairwise (bit-exact), dot = correctly-rounded fp32 of exact fp64 dot.
__global__ void refine_np_kernel(const float* __restrict__ z, const float* __restrict__ e,
                                 const float* __restrict__ e2np, const int* __restrict__ cand,
                                 int* __restrict__ widx) {
    __shared__ float buf[4][DDIM];
    __shared__ float ch[4][16];
    const int w = threadIdx.x >> 6;
    const int t = threadIdx.x & 63;
    const int n = blockIdx.x * 4 + w;

    float4 zv = *(const float4*)&z[(size_t)n * DDIM + t * 4];
    *(float4*)&buf[w][t * 4] = zv;
    __syncthreads();
    if (t < 16) ch[w][t] = np_sq_chain(buf[w], t);
    __syncthreads();

    float dotf[4];
    int   kc[4];
    #pragma unroll
    for (int c = 0; c < 4; ++c) {
        int k = cand[4 * n + c];
        kc[c] = k;
        float4 ev = *(const float4*)&e[(size_t)k * DDIM + t * 4];
        double p = (double)zv.x * (double)ev.x + (double)zv.y * (double)ev.y
                 + (double)zv.z * (double)ev.z + (double)zv.w * (double)ev.w;
        #pragma unroll
        for (int o = 32; o > 0; o >>= 1) p += __shfl_down(p, o);
        dotf[c] = (float)p;   // correctly-rounded fp32 of exact dot
    }

    if (t == 0) {
        #pragma clang fp contract(off)
        float sx = np_combine16(ch[w]);
        float bd = 3.4e38f;
        int   bk = 0x7fffffff;
        #pragma unroll
        for (int c = 0; c < 4; ++c) {
            float twod = 2.0f * dotf[c];
            float t1 = sx - twod;
            float d2v = t1 + e2np[kc[c]];
            d2v = fmaxf(d2v, 0.0f);
            float d = sqrtf(d2v);
            if (d < bd || (d == bd && kc[c] < bk)) { bd = d; bk = kc[c]; }
        }
        widx[n] = bk;
    }
}

// ---------------- kernel 4: gather z_q, sq-diff partial, histogram, idx ----------------
__global__ void gather_loss_kernel(const float* __restrict__ z, const float* __restrict__ e,
                                   const int* __restrict__ widx, int* __restrict__ counts,
                                   float* __restrict__ sqsum, float* __restrict__ out_zq,
                                   float* __restrict__ out_idx) {
    int n = blockIdx.x;
    int d = threadIdx.x;
    int k = widx[n];
    float q  = e[(size_t)k * DDIM + d];
    float ze = z[(size_t)n * DDIM + d];
    out_zq[(size_t)n * DDIM + d] = q;
    float diff = q - ze;
    float s = diff * diff;
    #pragma unroll
    for (int o = 32; o > 0; o >>= 1) s += __shfl_down(s, o);
    __shared__ float ps[4];
    if ((threadIdx.x & 63) == 0) ps[threadIdx.x >> 6] = s;
    __syncthreads();
    if (threadIdx.x == 0) {
        atomicAdd(sqsum, ps[0] + ps[1] + ps[2] + ps[3]);
        atomicAdd(&counts[k], 1);
        out_idx[n] = (float)k;
    }
}

// ---------------- kernel 5: finalize loss ----------------
__global__ void finalize_kernel(const int* __restrict__ counts, const float* __restrict__ sqsum,
                                float* __restrict__ out_loss, int K, float invN, float invND) {
    int t = threadIdx.x;
    double local = 0.0;
    for (int k = t; k < K; k += 256) {
        float p = (float)counts[k] * invN;
        local += (double)(p * logf(p + 1e-10f));
    }
    #pragma unroll
    for (int o = 32; o > 0; o >>= 1) local += __shfl_down(local, o);
    __shared__ double ps[4];
    if ((t & 63) == 0) ps[t >> 6] = local;
    __syncthreads();
    if (t == 0) {
        double s = ps[0] + ps[1] + ps[2] + ps[3];
        float perp = expf((float)(-s));
        float mean = (*sqsum) * invND;
        out_loss[0] = 1.25f * mean - 0.01f * perp;
    }
}

extern "C" void kernel_launch(void* const* d_in, const int* in_sizes, int n_in,
                              void* d_out, int out_size, void* d_ws, size_t ws_size,
                              hipStream_t stream) {
    const float* z = (const float*)d_in[0];
    const float* e = (const float*)d_in[1];
    const int N = in_sizes[0] / DDIM;   // 32768
    const int K = in_sizes[1] / DDIM;   // 2048

    float* out      = (float*)d_out;
    float* out_zq   = out;
    float* out_loss = out + (size_t)N * DDIM;
    float* out_idx  = out_loss + 1;

    // ws layout (4-byte words): counts[K] | sqsum[1] | e2np[K] | widx[N] | cand[4N]
    int*   counts = (int*)d_ws;
    float* sqsum  = (float*)d_ws + K;
    float* e2np   = (float*)d_ws + K + 1;
    int*   widx   = (int*)d_ws + 2 * K + 1;
    int*   cand   = widx + N;

    zero_ws_kernel<<<(K + 1 + 255) / 256, 256, 0, stream>>>(counts, sqsum, K);
    code_norms_np_kernel<<<K, 64, 0, stream>>>(e, e2np);
    vq_argmin_kernel<<<N / BN, 256, 0, stream>>>(z, e, e2np, cand, K);
    refine_np_kernel<<<N / 4, 256, 0, stream>>>(z, e, e2np, cand, widx);
    gather_loss_kernel<<<N, 256, 0, stream>>>(z, e, widx, counts, sqsum, out_zq, out_idx);
    finalize_kernel<<<1, 256, 0, stream>>>(counts, sqsum, out_loss, K,
                                           1.0f / (float)N, 1.0f / (float)(N * DDIM));
}

// Round 4
// 1088.564 us; speedup vs baseline: 1.2878x; 1.2878x over previous
//
#include <hip/hip_runtime.h>
#include <math.h>

#define DDIM 256
#define NROWS_TOTAL 32768
#define ZT 128            // z-rows per block
#define CT 128            // codes per tile
#define LDSS 264          // LDS row stride in shorts (256 + 8 pad -> 2-way banks max)
#define SMEM_BYTES (ZT * LDSS * 2 + CT * LDSS * 2 + CT * 4)  // 135680

typedef __attribute__((ext_vector_type(8))) short short8v;
typedef __attribute__((ext_vector_type(4))) float float4v;

// ---- RNE float -> bf16 ----
__device__ __forceinline__ short f2bf(float x) {
    unsigned u = __float_as_uint(x);
    u = u + 0x7fffu + ((u >> 16) & 1u);
    return (short)(u >> 16);
}

// ---- numpy pairwise-sum simulation (bit-faithful for n=256 contiguous) ----
__device__ __forceinline__ float np_sq_chain(const float* v, int lane) {
    #pragma clang fp contract(off)
    const int half = lane >> 3, j = lane & 7;
    const float* base = v + half * 128 + j;
    float x = base[0];
    float c = x * x;
    #pragma unroll
    for (int m = 1; m < 16; ++m) {
        float y = base[8 * m];
        float s = y * y;
        c = c + s;
    }
    return c;
}

__device__ __forceinline__ float np_combine16(const float* c) {
    #pragma clang fp contract(off)
    float L = ((c[0] + c[1]) + (c[2] + c[3])) + ((c[4] + c[5]) + (c[6] + c[7]));
    float R = ((c[8] + c[9]) + (c[10] + c[11])) + ((c[12] + c[13]) + (c[14] + c[15]));
    return L + R;
}

// ---------------- kernel 1: zero counts + sqsum ----------------
__global__ void zero_ws_kernel(int* __restrict__ counts, float* __restrict__ sqsum, int K) {
    int i = blockIdx.x * 256 + threadIdx.x;
    if (i < K) counts[i] = 0;
    if (i == K) *sqsum = 0.0f;
}

// ---------------- kernel 2: numpy-faithful code norms ||e_k||^2 ----------------
__global__ void code_norms_np_kernel(const float* __restrict__ e, float* __restrict__ e2) {
    __shared__ float buf[DDIM];
    __shared__ float ch[16];
    int k = blockIdx.x;
    int t = threadIdx.x;  // 64 threads = 1 wave
    float4 v = *(const float4*)&e[(size_t)k * DDIM + t * 4];
    *(float4*)&buf[t * 4] = v;
    __syncthreads();
    if (t < 16) ch[t] = np_sq_chain(buf, t);
    __syncthreads();
    if (t == 0) e2[k] = np_combine16(ch);
}

// ---------------- kernel 2b: convert e -> bf16 ----------------
__global__ void convert_bf16_kernel(const float* __restrict__ src, short* __restrict__ dst, int n8) {
    int i = blockIdx.x * 256 + threadIdx.x;   // chunk of 8 elements
    if (i >= n8) return;
    const float* s = src + (size_t)i * 8;
    float4 f0 = *(const float4*)s;
    float4 f1 = *(const float4*)(s + 4);
    short8v v;
    v[0] = f2bf(f0.x); v[1] = f2bf(f0.y); v[2] = f2bf(f0.z); v[3] = f2bf(f0.w);
    v[4] = f2bf(f1.x); v[5] = f2bf(f1.y); v[6] = f2bf(f1.z); v[7] = f2bf(f1.w);
    *(short8v*)(dst + (size_t)i * 8) = v;
}

// ---- top-3 insertion (strict <, preserves first-occurrence order) ----
__device__ __forceinline__ void ins3(float m, int k,
                                     float& v0, float& v1, float& v2,
                                     int& i0, int& i1, int& i2) {
    if (m < v0)      { v2 = v1; i2 = i1; v1 = v0; i1 = i0; v0 = m; i0 = k; }
    else if (m < v1) { v2 = v1; i2 = i1; v1 = m;  i1 = k; }
    else if (m < v2) { v2 = m;  i2 = k; }
}

// ---------------- kernel 3: bf16 MFMA candidate kernel ----------------
// A-operand = codes (streamed per tile), B-operand = z-rows (persistent LDS).
// C[m=code][n=zrow]; epilogue fuses m(k)=||e||^2-2S into per-thread top-3 per
// z-row, final LDS merge -> top-8 candidates per row.
__global__ __launch_bounds__(256)
void vq_cand_kernel(const float* __restrict__ z, const short* __restrict__ ebf,
                    const float* __restrict__ e2, int* __restrict__ cand, int K) {
    extern __shared__ char smem[];
    short* zs  = (short*)smem;                            // ZT x LDSS
    short* es  = (short*)(smem + ZT * LDSS * 2);          // CT x LDSS
    float* e2s = (float*)(smem + ZT * LDSS * 2 + CT * LDSS * 2);  // CT floats

    const int t    = threadIdx.x;
    const int w    = t >> 6;
    const int lane = t & 63;
    const int quad = lane >> 4;
    const int l15  = lane & 15;
    const int wm   = w & 1;    // code-dir half (0..1)
    const int wn   = w >> 1;   // z-row-dir half (0..1)
    const int row0 = blockIdx.x * ZT;

    // ---- stage z (f32 -> bf16) into zs, once ----
    #pragma unroll
    for (int p = 0; p < 16; ++p) {
        int c  = t + p * 256;      // chunk of 8 elems
        int r  = c >> 5;           // row 0..127
        int c8 = c & 31;           // 8-elem col
        const float* s = &z[(size_t)(row0 + r) * DDIM + c8 * 8];
        float4 f0 = *(const float4*)s;
        float4 f1 = *(const float4*)(s + 4);
        short8v v;
        v[0] = f2bf(f0.x); v[1] = f2bf(f0.y); v[2] = f2bf(f0.z); v[3] = f2bf(f0.w);
        v[4] = f2bf(f1.x); v[5] = f2bf(f1.y); v[6] = f2bf(f1.z); v[7] = f2bf(f1.w);
        *(short8v*)&zs[r * LDSS + c8 * 8] = v;
    }

    // per-thread top-3 per covered z-row (j = 0..3)
    float v0[4], v1[4], v2[4];
    int   i0[4], i1[4], i2[4];
    #pragma unroll
    for (int j = 0; j < 4; ++j) {
        v0[j] = 3.4e38f; v1[j] = 3.4e38f; v2[j] = 3.4e38f;
        i0[j] = 0x7fffffff; i1[j] = 0x7fffffff; i2[j] = 0x7fffffff;
    }

    #pragma unroll 1
    for (int kt = 0; kt < K; kt += CT) {
        __syncthreads();  // protect es/e2s from previous iteration's readers
        // ---- stage code tile (bf16, pre-converted) ----
        #pragma unroll
        for (int p = 0; p < 16; ++p) {
            int c  = t + p * 256;
            int r  = c >> 5;
            int c8 = c & 31;
            short8v v = *(const short8v*)&ebf[(size_t)(kt + r) * DDIM + c8 * 8];
            *(short8v*)&es[r * LDSS + c8 * 8] = v;
        }
        if (t < CT) e2s[t] = e2[kt + t];
        __syncthreads();

        float4v acc[4][4];
        #pragma unroll
        for (int i = 0; i < 4; ++i)
            #pragma unroll
            for (int j = 0; j < 4; ++j)
                acc[i][j] = (float4v)0.0f;

        #pragma unroll
        for (int k0 = 0; k0 < DDIM; k0 += 32) {
            short8v a[4], b[4];
            #pragma unroll
            for (int i = 0; i < 4; ++i)
                a[i] = *(short8v*)&es[(wm * 64 + i * 16 + l15) * LDSS + k0 + quad * 8];
            #pragma unroll
            for (int j = 0; j < 4; ++j)
                b[j] = *(short8v*)&zs[(wn * 64 + j * 16 + l15) * LDSS + k0 + quad * 8];
            #pragma unroll
            for (int i = 0; i < 4; ++i)
                #pragma unroll
                for (int j = 0; j < 4; ++j)
                    acc[i][j] = __builtin_amdgcn_mfma_f32_16x16x32_bf16(a[i], b[j], acc[i][j], 0, 0, 0);
        }

        // ---- epilogue: fold this code tile into per-row top-3 ----
        #pragma unroll
        for (int i = 0; i < 4; ++i) {
            #pragma unroll
            for (int reg = 0; reg < 4; ++reg) {
                int cl = wm * 64 + i * 16 + quad * 4 + reg;  // code within tile
                float ev = e2s[cl];
                int   kc = kt + cl;
                #pragma unroll
                for (int j = 0; j < 4; ++j) {
                    float m = fmaf(-2.0f, acc[i][j][reg], ev);
                    ins3(m, kc, v0[j], v1[j], v2[j], i0[j], i1[j], i2[j]);
                }
            }
        }
    }

    // ---- final merge: 8 threads x top-3 = 24 entries per z-row -> top-8 ----
    __syncthreads();
    float* mv = (float*)zs;   // [ZT][24]
    int*   mi = (int*)es;     // [ZT][24]
    #pragma unroll
    for (int j = 0; j < 4; ++j) {
        int rl   = wn * 64 + j * 16 + l15;
        int slot = wm * 12 + quad * 3;
        mv[rl * 24 + slot]     = v0[j];  mi[rl * 24 + slot]     = i0[j];
        mv[rl * 24 + slot + 1] = v1[j];  mi[rl * 24 + slot + 1] = i1[j];
        mv[rl * 24 + slot + 2] = v2[j];  mi[rl * 24 + slot + 2] = i2[j];
    }
    __syncthreads();
    if (t < ZT) {
        float bv[8]; int bi[8];
        #pragma unroll
        for (int c = 0; c < 8; ++c) { bv[c] = 3.4e38f; bi[c] = 0x7fffffff; }
        for (int s = 0; s < 24; ++s) {
            float v  = mv[t * 24 + s];
            int   id = mi[t * 24 + s];
            #pragma unroll
            for (int c = 0; c < 8; ++c) {
                if (v < bv[c] || (v == bv[c] && id < bi[c])) {
                    for (int d = 7; d > c; --d) { bv[d] = bv[d - 1]; bi[d] = bi[d - 1]; }
                    bv[c] = v; bi[c] = id;
                    break;
                }
            }
        }
        #pragma unroll
        for (int c = 0; c < 8; ++c) cand[(size_t)(row0 + t) * 8 + c] = bi[c];
    }
}

// ---------------- kernel 3b: numpy-fp32-faithful re-ranking of top-8 ----------------
__global__ void refine_np_kernel(const float* __restrict__ z, const float* __restrict__ e,
                                 const float* __restrict__ e2np, const int* __restrict__ cand,
                                 int* __restrict__ widx) {
    __shared__ float buf[4][DDIM];
    __shared__ float ch[4][16];
    const int w = threadIdx.x >> 6;
    const int t = threadIdx.x & 63;
    const int n = blockIdx.x * 4 + w;

    float4 zv = *(const float4*)&z[(size_t)n * DDIM + t * 4];
    *(float4*)&buf[w][t * 4] = zv;
    __syncthreads();
    if (t < 16) ch[w][t] = np_sq_chain(buf[w], t);
    __syncthreads();

    float dotf[8];
    int   kc[8];
    #pragma unroll
    for (int c = 0; c < 8; ++c) {
        int k = cand[(size_t)n * 8 + c];
        kc[c] = k;
        float4 ev = *(const float4*)&e[(size_t)k * DDIM + t * 4];
        double p = (double)zv.x * (double)ev.x + (double)zv.y * (double)ev.y
                 + (double)zv.z * (double)ev.z + (double)zv.w * (double)ev.w;
        #pragma unroll
        for (int o = 32; o > 0; o >>= 1) p += __shfl_down(p, o);
        dotf[c] = (float)p;   // correctly-rounded fp32 of exact dot
    }

    if (t == 0) {
        #pragma clang fp contract(off)
        float sx = np_combine16(ch[w]);
        float bd = 3.4e38f;
        int   bk = 0x7fffffff;
        #pragma unroll
        for (int c = 0; c < 8; ++c) {
            float twod = 2.0f * dotf[c];
            float t1 = sx - twod;
            float d2v = t1 + e2np[kc[c]];
            d2v = fmaxf(d2v, 0.0f);
            float d = sqrtf(d2v);
            if (d < bd || (d == bd && kc[c] < bk)) { bd = d; bk = kc[c]; }
        }
        widx[n] = bk;
    }
}

// ---------------- kernel 4: gather z_q, sq-diff partial, histogram, idx ----------------
__global__ void gather_loss_kernel(const float* __restrict__ z, const float* __restrict__ e,
                                   const int* __restrict__ widx, int* __restrict__ counts,
                                   float* __restrict__ sqsum, float* __restrict__ out_zq,
                                   float* __restrict__ out_idx) {
    int n = blockIdx.x;
    int d = threadIdx.x;
    int k = widx[n];
    float q  = e[(size_t)k * DDIM + d];
    float ze = z[(size_t)n * DDIM + d];
    out_zq[(size_t)n * DDIM + d] = q;
    float diff = q - ze;
    float s = diff * diff;
    #pragma unroll
    for (int o = 32; o > 0; o >>= 1) s += __shfl_down(s, o);
    __shared__ float ps[4];
    if ((threadIdx.x & 63) == 0) ps[threadIdx.x >> 6] = s;
    __syncthreads();
    if (threadIdx.x == 0) {
        atomicAdd(sqsum, ps[0] + ps[1] + ps[2] + ps[3]);
        atomicAdd(&counts[k], 1);
        out_idx[n] = (float)k;
    }
}

// ---------------- kernel 5: finalize loss ----------------
__global__ void finalize_kernel(const int* __restrict__ counts, const float* __restrict__ sqsum,
                                float* __restrict__ out_loss, int K, float invN, float invND) {
    int t = threadIdx.x;
    double local = 0.0;
    for (int k = t; k < K; k += 256) {
        float p = (float)counts[k] * invN;
        local += (double)(p * logf(p + 1e-10f));
    }
    #pragma unroll
    for (int o = 32; o > 0; o >>= 1) local += __shfl_down(local, o);
    __shared__ double ps[4];
    if ((t & 63) == 0) ps[t >> 6] = local;
    __syncthreads();
    if (t == 0) {
        double s = ps[0] + ps[1] + ps[2] + ps[3];
        float perp = expf((float)(-s));
        float mean = (*sqsum) * invND;
        out_loss[0] = 1.25f * mean - 0.01f * perp;
    }
}

extern "C" void kernel_launch(void* const* d_in, const int* in_sizes, int n_in,
                              void* d_out, int out_size, void* d_ws, size_t ws_size,
                              hipStream_t stream) {
    const float* z = (const float*)d_in[0];
    const float* e = (const float*)d_in[1];
    const int N = in_sizes[0] / DDIM;   // 32768
    const int K = in_sizes[1] / DDIM;   // 2048

    float* out      = (float*)d_out;
    float* out_zq   = out;
    float* out_loss = out + (size_t)N * DDIM;
    float* out_idx  = out_loss + 1;

    // ws layout (int words): counts[K]@0 | sqsum@2048 | pad | e2np[K]@2052 |
    //                        widx[N]@4100 | cand[8N]@36868 | ebf(shorts)@299012
    int*   counts = (int*)d_ws;
    float* sqsum  = (float*)d_ws + K;
    float* e2np   = (float*)d_ws + 2052;
    int*   widx   = (int*)d_ws + 4100;
    int*   cand   = (int*)d_ws + 36868;
    short* ebf    = (short*)((int*)d_ws + 299012);   // byte off 1196048, 16B-aligned

    hipFuncSetAttribute((const void*)vq_cand_kernel,
                        hipFuncAttributeMaxDynamicSharedMemorySize, SMEM_BYTES);

    zero_ws_kernel<<<(K + 1 + 255) / 256, 256, 0, stream>>>(counts, sqsum, K);
    code_norms_np_kernel<<<K, 64, 0, stream>>>(e, e2np);
    convert_bf16_kernel<<<(K * DDIM / 8 + 255) / 256, 256, 0, stream>>>(e, ebf, K * DDIM / 8);
    vq_cand_kernel<<<N / ZT, 256, SMEM_BYTES, stream>>>(z, ebf, e2np, cand, K);
    refine_np_kernel<<<N / 4, 256, 0, stream>>>(z, e, e2np, cand, widx);
    gather_loss_kernel<<<N, 256, 0, stream>>>(z, e, widx, counts, sqsum, out_zq, out_idx);
    finalize_kernel<<<1, 256, 0, stream>>>(counts, sqsum, out_loss, K,
                                           1.0f / (float)N, 1.0f / (float)(N * DDIM));
}

// Round 5
// 495.134 us; speedup vs baseline: 2.8313x; 2.1985x over previous
//
#include <hip/hip_runtime.h>
#include <math.h>

#define DDIM 256
#define NSPLIT 4
#define TILES_PER_SPLIT 16   // 16 tiles x 32 codes = 512 codes per split
#define TILE_CODES 32
#define TILE_BYTES 16384     // 32 codes x 256 dims x 2B (panel layout)
#define SMEM_BYTES 32768     // double-buffered tile

typedef __attribute__((ext_vector_type(8))) short short8v;
typedef __attribute__((ext_vector_type(4))) float float4v;
typedef unsigned int u32;
typedef unsigned short u16;

// ---- RNE float -> bf16 ----
__device__ __forceinline__ short f2bf(float x) {
    u32 u = __float_as_uint(x);
    u = u + 0x7fffu + ((u >> 16) & 1u);
    return (short)(u >> 16);
}

// ---- async global->LDS, 16B per lane; lds dst = wave-uniform base + lane*16 ----
__device__ __forceinline__ void gload_lds16(const void* g, void* l) {
    __builtin_amdgcn_global_load_lds(
        (const __attribute__((address_space(1))) u32*)g,
        (__attribute__((address_space(3))) u32*)l, 16, 0, 0);
}

// ---- numpy pairwise-sum simulation (bit-faithful for n=256 contiguous) ----
__device__ __forceinline__ float np_sq_chain(const float* v, int lane) {
    #pragma clang fp contract(off)
    const int half = lane >> 3, j = lane & 7;
    const float* base = v + half * 128 + j;
    float x = base[0];
    float c = x * x;
    #pragma unroll
    for (int m = 1; m < 16; ++m) {
        float y = base[8 * m];
        float s = y * y;
        c = c + s;
    }
    return c;
}

__device__ __forceinline__ float np_combine16(const float* c) {
    #pragma clang fp contract(off)
    float L = ((c[0] + c[1]) + (c[2] + c[3])) + ((c[4] + c[5]) + (c[6] + c[7]));
    float R = ((c[8] + c[9]) + (c[10] + c[11])) + ((c[12] + c[13]) + (c[14] + c[15]));
    return L + R;
}

// ---- top-3 insertion (strict <, preserves first-occurrence order) ----
__device__ __forceinline__ void ins3(float m, int k,
                                     float& v0, float& v1, float& v2,
                                     int& i0, int& i1, int& i2) {
    if (m < v0)      { v2 = v1; i2 = i1; v1 = v0; i1 = i0; v0 = m; i0 = k; }
    else if (m < v1) { v2 = v1; i2 = i1; v1 = m;  i1 = k; }
    else if (m < v2) { v2 = m;  i2 = k; }
}

// ---------------- kernel 1: zero counts ----------------
__global__ void zero_counts_kernel(int* __restrict__ counts, int K) {
    int i = blockIdx.x * 256 + threadIdx.x;
    if (i < K) counts[i] = 0;
}

// ---------------- kernel 2: numpy-faithful code norms ||e_k||^2 ----------------
__global__ void code_norms_np_kernel(const float* __restrict__ e, float* __restrict__ e2) {
    __shared__ float buf[DDIM];
    __shared__ float ch[16];
    int k = blockIdx.x;
    int t = threadIdx.x;  // 64 threads = 1 wave
    float4 v = *(const float4*)&e[(size_t)k * DDIM + t * 4];
    *(float4*)&buf[t * 4] = v;
    __syncthreads();
    if (t < 16) ch[t] = np_sq_chain(buf, t);
    __syncthreads();
    if (t == 0) e2[k] = np_combine16(ch);
}

// ---------------- kernel 2b: convert e -> bf16 panel layout ----------------
// ebf_p[tile=k/32][d8=0..31][r=k%32][8 shorts]; tile = 16KB contiguous.
__global__ void convert_permute_e_kernel(const float* __restrict__ e, char* __restrict__ ebf_p) {
    int id = blockIdx.x * 256 + threadIdx.x;   // id = k*32 + d8, total K*32
    int k = id >> 5, d8 = id & 31;
    const float* s = &e[(size_t)k * DDIM + d8 * 8];
    float4 f0 = *(const float4*)s;
    float4 f1 = *(const float4*)(s + 4);
    short8v v;
    v[0] = f2bf(f0.x); v[1] = f2bf(f0.y); v[2] = f2bf(f0.z); v[3] = f2bf(f0.w);
    v[4] = f2bf(f1.x); v[5] = f2bf(f1.y); v[6] = f2bf(f1.z); v[7] = f2bf(f1.w);
    *(short8v*)(ebf_p + ((size_t)(k >> 5) << 14) + d8 * 512 + (k & 31) * 16) = v;
}

// ---------------- kernel 3: bf16 MFMA candidate kernel ----------------
// grid = (N/256, 4 splits). Block = 4 waves; wave owns 64 z-rows (register-
// resident bf16 B-fragments). Codes double-buffered in LDS via global_load_lds.
// Emits per-split top-3 per row -> cand[row][split*3 + c].
__global__ __launch_bounds__(256, 2)
void vq_cand_kernel(const float* __restrict__ z, const char* __restrict__ ebf_p,
                    const float* __restrict__ e2, u16* __restrict__ cand) {
    extern __shared__ char smem[];
    const int t    = threadIdx.x;
    const int w    = t >> 6;
    const int lane = t & 63;
    const int quad = lane >> 4;
    const int l15  = lane & 15;
    const int s    = blockIdx.y;
    const int row0 = blockIdx.x * 256;
    const int rw0  = row0 + w * 64;

    // ---- persistent z fragments: 64 rows x 256 dims per wave ----
    short8v zf[4][8];
    #pragma unroll
    for (int j = 0; j < 4; ++j) {
        const float* zr = &z[(size_t)(rw0 + j * 16 + l15) * DDIM];
        #pragma unroll
        for (int kk = 0; kk < 8; ++kk) {
            int d0 = kk * 32 + quad * 8;
            float4 f0 = *(const float4*)&zr[d0];
            float4 f1 = *(const float4*)&zr[d0 + 4];
            short8v v;
            v[0] = f2bf(f0.x); v[1] = f2bf(f0.y); v[2] = f2bf(f0.z); v[3] = f2bf(f0.w);
            v[4] = f2bf(f1.x); v[5] = f2bf(f1.y); v[6] = f2bf(f1.z); v[7] = f2bf(f1.w);
            zf[j][kk] = v;
        }
    }

    float v0[4], v1[4], v2[4];
    int   i0[4], i1[4], i2[4];
    #pragma unroll
    for (int j = 0; j < 4; ++j) {
        v0[j] = 3.4e38f; v1[j] = 3.4e38f; v2[j] = 3.4e38f;
        i0[j] = 0x7fff;  i1[j] = 0x7fff;  i2[j] = 0x7fff;
    }

    const char* tile_base = ebf_p + (size_t)s * TILES_PER_SPLIT * TILE_BYTES;

    // prefetch tile 0 into buf0
    {
        const char* src = tile_base + w * 4096 + lane * 16;
        char* dst = smem + w * 4096;
        #pragma unroll
        for (int q = 0; q < 4; ++q) gload_lds16(src + q * 1024, dst + q * 1024);
    }
    __syncthreads();

    #pragma unroll 1
    for (int tt = 0; tt < TILES_PER_SPLIT; ++tt) {
        // issue next tile's loads into the other buffer (drained at loop-end barrier)
        if (tt + 1 < TILES_PER_SPLIT) {
            const char* src = tile_base + (size_t)(tt + 1) * TILE_BYTES + w * 4096 + lane * 16;
            char* dst = smem + ((tt + 1) & 1) * TILE_BYTES + w * 4096;
            #pragma unroll
            for (int q = 0; q < 4; ++q) gload_lds16(src + q * 1024, dst + q * 1024);
        }
        const short* es = (const short*)(smem + (tt & 1) * TILE_BYTES);

        float4v acc[2][4];
        #pragma unroll
        for (int i = 0; i < 2; ++i)
            #pragma unroll
            for (int j = 0; j < 4; ++j) acc[i][j] = (float4v)0.0f;

        #pragma unroll
        for (int kk = 0; kk < 8; ++kk) {
            int c = kk * 4 + quad;  // d8 chunk
            short8v a0 = *(const short8v*)&es[c * 256 + l15 * 8];        // codes 0..15
            short8v a1 = *(const short8v*)&es[c * 256 + (16 + l15) * 8]; // codes 16..31
            #pragma unroll
            for (int j = 0; j < 4; ++j) {
                acc[0][j] = __builtin_amdgcn_mfma_f32_16x16x32_bf16(a0, zf[j][kk], acc[0][j], 0, 0, 0);
                acc[1][j] = __builtin_amdgcn_mfma_f32_16x16x32_bf16(a1, zf[j][kk], acc[1][j], 0, 0, 0);
            }
        }

        // epilogue: fold tile scores into per-row top-3
        const int kbase = s * 512 + tt * TILE_CODES;
        #pragma unroll
        for (int i = 0; i < 2; ++i) {
            #pragma unroll
            for (int reg = 0; reg < 4; ++reg) {
                int cl = i * 16 + quad * 4 + reg;
                float ev = e2[kbase + cl];
                int   kc = kbase + cl;
                #pragma unroll
                for (int j = 0; j < 4; ++j) {
                    float m = fmaf(-2.0f, acc[i][j][reg], ev);
                    ins3(m, kc, v0[j], v1[j], v2[j], i0[j], i1[j], i2[j]);
                }
            }
        }
        __syncthreads();  // drains next-tile loads; guards buffer reuse
    }

    // ---- merge: per row, 4 quads x top-3 = 12 entries -> top-3 of split ----
    float* mv = (float*)smem;              // [256][12] floats (12 KB)
    short* mi = (short*)(smem + 12288);    // [256][12] shorts (6 KB)
    #pragma unroll
    for (int j = 0; j < 4; ++j) {
        int rl = w * 64 + j * 16 + l15;
        int sl = quad * 3;
        mv[rl * 12 + sl]     = v0[j];  mi[rl * 12 + sl]     = (short)i0[j];
        mv[rl * 12 + sl + 1] = v1[j];  mi[rl * 12 + sl + 1] = (short)i1[j];
        mv[rl * 12 + sl + 2] = v2[j];  mi[rl * 12 + sl + 2] = (short)i2[j];
    }
    __syncthreads();
    {
        float bv0 = 3.4e38f, bv1 = 3.4e38f, bv2 = 3.4e38f;
        int   bi0 = 0x7fff,  bi1 = 0x7fff,  bi2 = 0x7fff;
        for (int x = 0; x < 12; ++x) {
            float m  = mv[t * 12 + x];
            int   k2 = (int)mi[t * 12 + x];
            if (m < bv0 || (m == bv0 && k2 < bi0)) {
                bv2 = bv1; bi2 = bi1; bv1 = bv0; bi1 = bi0; bv0 = m; bi0 = k2;
            } else if (m < bv1 || (m == bv1 && k2 < bi1)) {
                bv2 = bv1; bi2 = bi1; bv1 = m; bi1 = k2;
            } else if (m < bv2 || (m == bv2 && k2 < bi2)) {
                bv2 = m; bi2 = k2;
            }
        }
        u16* cp = &cand[(size_t)(row0 + t) * 12 + s * 3];
        cp[0] = (u16)bi0; cp[1] = (u16)bi1; cp[2] = (u16)bi2;
    }
}

// ---------------- kernel 4: fused np-faithful re-rank + gather + loss partials ----------------
// One wave per row. Re-ranks 12 candidates with numpy-fp32-faithful distance,
// writes z_q row + idx, atomically bumps counts, per-block sq partial (no
// same-address float atomics).
__global__ void refine_fused_kernel(const float* __restrict__ z, const float* __restrict__ e,
                                    const float* __restrict__ e2np, const u16* __restrict__ cand,
                                    int* __restrict__ counts, float* __restrict__ partials,
                                    float* __restrict__ out_zq, float* __restrict__ out_idx) {
    __shared__ float buf[4][DDIM];
    __shared__ float ch[4][16];
    __shared__ float wsum[4];
    const int w = threadIdx.x >> 6;
    const int t = threadIdx.x & 63;
    const int n = blockIdx.x * 4 + w;

    float4 zv = *(const float4*)&z[(size_t)n * DDIM + t * 4];
    *(float4*)&buf[w][t * 4] = zv;
    __syncthreads();
    if (t < 16) ch[w][t] = np_sq_chain(buf[w], t);
    __syncthreads();

    float dotf[12];
    int   kc[12];
    #pragma unroll
    for (int c = 0; c < 12; ++c) {
        int k = cand[(size_t)n * 12 + c];
        kc[c] = k;
        float4 ev = *(const float4*)&e[(size_t)k * DDIM + t * 4];
        double p = (double)zv.x * (double)ev.x + (double)zv.y * (double)ev.y
                 + (double)zv.z * (double)ev.z + (double)zv.w * (double)ev.w;
        #pragma unroll
        for (int o = 32; o > 0; o >>= 1) p += __shfl_down(p, o);
        dotf[c] = (float)p;   // correctly-rounded fp32 of exact dot
    }

    int bk = 0;
    if (t == 0) {
        #pragma clang fp contract(off)
        float sx = np_combine16(ch[w]);
        float bd = 3.4e38f;
        bk = 0x7fffffff;
        #pragma unroll
        for (int c = 0; c < 12; ++c) {
            float twod = 2.0f * dotf[c];
            float t1 = sx - twod;
            float d2v = t1 + e2np[kc[c]];
            d2v = fmaxf(d2v, 0.0f);
            float d = sqrtf(d2v);
            if (d < bd || (d == bd && kc[c] < bk)) { bd = d; bk = kc[c]; }
        }
    }
    int wk = __shfl(bk, 0);

    float4 ev = *(const float4*)&e[(size_t)wk * DDIM + t * 4];
    *(float4*)&out_zq[(size_t)n * DDIM + t * 4] = ev;
    float dx = zv.x - ev.x, dy = zv.y - ev.y, dz = zv.z - ev.z, dw = zv.w - ev.w;
    float sq = dx * dx + dy * dy + dz * dz + dw * dw;
    #pragma unroll
    for (int o = 32; o > 0; o >>= 1) sq += __shfl_down(sq, o);
    if (t == 0) {
        wsum[w] = sq;
        atomicAdd(&counts[wk], 1);
        out_idx[n] = (float)wk;
    }
    __syncthreads();
    if (threadIdx.x == 0)
        partials[blockIdx.x] = wsum[0] + wsum[1] + wsum[2] + wsum[3];
}

// ---------------- kernel 5: finalize loss ----------------
__global__ void finalize_kernel(const int* __restrict__ counts, const float* __restrict__ partials,
                                float* __restrict__ out_loss, int K, int NB,
                                float invN, float invND) {
    int t = threadIdx.x;
    double ent = 0.0, sq = 0.0;
    for (int k = t; k < K; k += 256) {
        float p = (float)counts[k] * invN;
        ent += (double)(p * logf(p + 1e-10f));
    }
    for (int i = t; i < NB; i += 256) sq += (double)partials[i];
    #pragma unroll
    for (int o = 32; o > 0; o >>= 1) {
        ent += __shfl_down(ent, o);
        sq  += __shfl_down(sq, o);
    }
    __shared__ double e4[4], s4[4];
    if ((t & 63) == 0) { e4[t >> 6] = ent; s4[t >> 6] = sq; }
    __syncthreads();
    if (t == 0) {
        double esum = e4[0] + e4[1] + e4[2] + e4[3];
        double ssum = s4[0] + s4[1] + s4[2] + s4[3];
        float perp = expf((float)(-esum));
        float mean = (float)ssum * invND;
        out_loss[0] = 1.25f * mean - 0.01f * perp;
    }
}

extern "C" void kernel_launch(void* const* d_in, const int* in_sizes, int n_in,
                              void* d_out, int out_size, void* d_ws, size_t ws_size,
                              hipStream_t stream) {
    const float* z = (const float*)d_in[0];
    const float* e = (const float*)d_in[1];
    const int N = in_sizes[0] / DDIM;   // 32768
    const int K = in_sizes[1] / DDIM;   // 2048

    float* out      = (float*)d_out;
    float* out_zq   = out;
    float* out_loss = out + (size_t)N * DDIM;
    float* out_idx  = out_loss + 1;

    // ws layout (bytes): counts[K]@0 (8K) | e2np[K]@8192 (8K) | partials[N/4]@16384 (32K)
    //                    | cand[N*12 u16]@49152 (768K) | ebf_p@835584 (1M)  => ~1.83MB total
    int*   counts   = (int*)d_ws;
    float* e2np     = (float*)((char*)d_ws + 8192);
    float* partials = (float*)((char*)d_ws + 16384);
    u16*   cand     = (u16*)((char*)d_ws + 49152);
    char*  ebf_p    = (char*)d_ws + 835584;

    zero_counts_kernel<<<(K + 255) / 256, 256, 0, stream>>>(counts, K);
    code_norms_np_kernel<<<K, 64, 0, stream>>>(e, e2np);
    convert_permute_e_kernel<<<K * 32 / 256, 256, 0, stream>>>(e, ebf_p);
    vq_cand_kernel<<<dim3(N / 256, NSPLIT), 256, SMEM_BYTES, stream>>>(z, ebf_p, e2np, cand);
    refine_fused_kernel<<<N / 4, 256, 0, stream>>>(z, e, e2np, cand, counts, partials,
                                                   out_zq, out_idx);
    finalize_kernel<<<1, 256, 0, stream>>>(counts, partials, out_loss, K, N / 4,
                                           1.0f / (float)N, 1.0f / (float)(N * DDIM));
}